// Round 1
// baseline (2467.885 us; speedup 1.0000x reference)
//
#include <hip/hip_runtime.h>
#include <cstdio>
#include <cstdint>

#define N_NODES 50000
#define N_EDGES 500000
#define EMB 128
#define BOND 64
#define NGRAPH 256

__device__ __forceinline__ unsigned short f2bf(float v){
  unsigned u = __float_as_uint(v);
  unsigned r = (u + 0x7fffu + ((u >> 16) & 1u)) >> 16;  // RNE
  return (unsigned short)r;
}
__device__ __forceinline__ float bf2f(unsigned short u){
  return __uint_as_float(((unsigned)u) << 16);
}

// out[r][c] = sum_k in[r][k] * W[c][k] + bias[c]
// W is [CO][K] row-major. Weights staged transposed in LDS (k-chunked, <64KB static).
// Thread blocking: 4 rows x 4 cols (float4 wT read, broadcast inT read).
template<int K, int CO, bool BF16OUT>
__global__ __launch_bounds__(256) void gemm_bias(const float* __restrict__ in,
    const float* __restrict__ W, const float* __restrict__ bias,
    void* __restrict__ outp, long M)
{
  constexpr int KC = (K > 64) ? 64 : K;
  constexpr int NKC = K / KC;
  constexpr int LANES = CO / 4;         // threads per row (32 for CO=128)
  constexpr int GROUPS = 256 / LANES;   // row-groups per block
  constexpr int RPB = GROUPS * 4;       // rows per block tile (32)
  constexpr int ISTR = K + 1;           // pad: group stride 4*(K+1) = 4 mod 32 -> banks spread
  __shared__ float wT[KC * CO];         // wT[k][c]
  __shared__ float inT[RPB * ISTR];
  const int t = threadIdx.x;
  const int lc = t % LANES, g = t / LANES;
  const int c0 = lc * 4;
  const float4 bv = *(const float4*)(bias + c0);

  for (long r0 = (long)blockIdx.x * RPB; r0 < M; r0 += (long)gridDim.x * RPB){
    __syncthreads();  // protect inT/wT from previous iteration's readers
    for (int i = t; i < RPB * K; i += 256){
      int rr = i / K, k = i % K;
      long r = r0 + rr;
      inT[rr * ISTR + k] = (r < M) ? in[r * (long)K + k] : 0.f;
    }
    float acc[4][4];
    #pragma unroll
    for (int rr = 0; rr < 4; rr++){
      acc[rr][0] = bv.x; acc[rr][1] = bv.y; acc[rr][2] = bv.z; acc[rr][3] = bv.w;
    }
    for (int kc = 0; kc < NKC; kc++){
      __syncthreads();
      // load W chunk transposed: consecutive threads -> consecutive c (conflict-free LDS
      // writes); global reads stride K but L1-resident after first sweep.
      for (int i = t; i < KC * CO; i += 256){
        int c = i % CO, k = i / CO;
        wT[k * CO + c] = W[c * K + kc * KC + k];
      }
      __syncthreads();
      #pragma unroll 8
      for (int k = 0; k < KC; k++){
        float4 w = *(const float4*)&wT[k * CO + c0];
        #pragma unroll
        for (int rr = 0; rr < 4; rr++){
          float a = inT[(g * 4 + rr) * ISTR + kc * KC + k];
          acc[rr][0] = fmaf(a, w.x, acc[rr][0]);
          acc[rr][1] = fmaf(a, w.y, acc[rr][1]);
          acc[rr][2] = fmaf(a, w.z, acc[rr][2]);
          acc[rr][3] = fmaf(a, w.w, acc[rr][3]);
        }
      }
    }
    #pragma unroll
    for (int rr = 0; rr < 4; rr++){
      long r = r0 + g * 4 + rr;
      if (r < M){
        if (BF16OUT){
          ushort4 o;
          o.x = f2bf(acc[rr][0]); o.y = f2bf(acc[rr][1]);
          o.z = f2bf(acc[rr][2]); o.w = f2bf(acc[rr][3]);
          *(ushort4*)((unsigned short*)outp + r * CO + c0) = o;
        } else {
          float4 o = make_float4(acc[rr][0], acc[rr][1], acc[rr][2], acc[rr][3]);
          *(float4*)((float*)outp + r * CO + c0) = o;
        }
      }
    }
  }
}

// node_new[dst] += node_old[src] * edge_emb[e]   (node_new pre-initialized = node_old)
// 32 lanes per edge, 4 channels per lane, f32 atomics.
__global__ __launch_bounds__(256) void msg_kernel(const float* __restrict__ node_old,
    const unsigned short* __restrict__ eemb, const int* __restrict__ ei,
    float* __restrict__ node_new)
{
  long e = (long)blockIdx.x * 8 + (threadIdx.x >> 5);
  if (e >= N_EDGES) return;
  int c0 = (threadIdx.x & 31) * 4;
  int src = ei[e];
  int dst = ei[N_EDGES + e];
  const float4 a = *(const float4*)(node_old + (long)src * EMB + c0);
  ushort4 eb = *(const ushort4*)(eemb + e * (long)EMB + c0);
  float m0 = a.x * bf2f(eb.x);
  float m1 = a.y * bf2f(eb.y);
  float m2 = a.z * bf2f(eb.z);
  float m3 = a.w * bf2f(eb.w);
  float* p = node_new + (long)dst * EMB + c0;
  atomicAdd(p + 0, m0);
  atomicAdd(p + 1, m1);
  atomicAdd(p + 2, m2);
  atomicAdd(p + 3, m3);
}

// Pre-transpose MLP weights into ws so mlp_pool reads them coalesced from global.
__global__ void transpose_w(const float* __restrict__ W1, const float* __restrict__ W2,
                            float* __restrict__ w1T, float* __restrict__ w2T)
{
  int i = blockIdx.x * 256 + threadIdx.x;
  if (i < EMB * EMB){
    int k = i >> 7, c = i & 127;
    w1T[i] = W1[c * EMB + k];          // w1T[k][c]
  } else {
    int j = i - EMB * EMB;
    if (j < 64 * EMB){
      int k = j >> 6, c = j & 63;
      w2T[j] = W2[c * EMB + k];        // w2T[k][c]
    }
  }
}

// Fused: relu -> W1 -> relu -> W2 -> relu -> W3 -> atomic pool into dg[256].
// One wave processes 8 nodes at a time (amortizes W1T/W2T global reads 8x).
__global__ __launch_bounds__(256) void mlp_pool(const float* __restrict__ ne,
    const float* __restrict__ w1T, const float* __restrict__ b1,
    const float* __restrict__ w2T, const float* __restrict__ b2,
    const float* __restrict__ W3, const int* __restrict__ batch,
    float* __restrict__ dg)
{
  __shared__ float h0s[4][8 * EMB];   // per-wave scratch, no cross-wave sharing
  __shared__ float h1s[4][8 * EMB];
  const int t = threadIdx.x;
  const int wid = t >> 6, l = t & 63;
  const long totalWaves = (long)gridDim.x * 4;
  const float b1a = b1[l], b1b = b1[64 + l];
  const float b2v = b2[l];
  const float w3v = W3[l];

  for (long n0 = ((long)blockIdx.x * 4 + wid) * 8; n0 < N_NODES; n0 += totalWaves * 8){
    int cnt = (int)((N_NODES - n0) < 8 ? (N_NODES - n0) : 8);
    #pragma unroll
    for (int j = 0; j < 8; j++){
      float v0 = 0.f, v1 = 0.f;
      if (j < cnt){
        v0 = fmaxf(ne[(n0 + j) * (long)EMB + l], 0.f);
        v1 = fmaxf(ne[(n0 + j) * (long)EMB + 64 + l], 0.f);
      }
      h0s[wid][j * EMB + l] = v0;
      h0s[wid][j * EMB + 64 + l] = v1;
    }
    float acc1a[8], acc1b[8];
    #pragma unroll
    for (int j = 0; j < 8; j++){ acc1a[j] = b1a; acc1b[j] = b1b; }
    for (int k = 0; k < EMB; k++){
      float wa = w1T[k * EMB + l];
      float wb = w1T[k * EMB + 64 + l];
      #pragma unroll
      for (int j = 0; j < 8; j++){
        float a = h0s[wid][j * EMB + k];   // LDS broadcast
        acc1a[j] = fmaf(a, wa, acc1a[j]);
        acc1b[j] = fmaf(a, wb, acc1b[j]);
      }
    }
    #pragma unroll
    for (int j = 0; j < 8; j++){
      h1s[wid][j * EMB + l] = fmaxf(acc1a[j], 0.f);
      h1s[wid][j * EMB + 64 + l] = fmaxf(acc1b[j], 0.f);
    }
    float acc2[8];
    #pragma unroll
    for (int j = 0; j < 8; j++) acc2[j] = b2v;
    for (int k = 0; k < EMB; k++){
      float w2 = w2T[k * 64 + l];
      #pragma unroll
      for (int j = 0; j < 8; j++)
        acc2[j] = fmaf(h1s[wid][j * EMB + k], w2, acc2[j]);
    }
    #pragma unroll
    for (int j = 0; j < 8; j++){
      float ev = fmaxf(acc2[j], 0.f) * w3v;
      #pragma unroll
      for (int off = 32; off > 0; off >>= 1) ev += __shfl_down(ev, off, 64);
      if (l == 0 && j < cnt) atomicAdd(&dg[batch[n0 + j]], ev);
    }
  }
}

extern "C" void kernel_launch(void* const* d_in, const int* in_sizes, int n_in,
                              void* d_out, int out_size, void* d_ws, size_t ws_size,
                              hipStream_t stream)
{
  const float* x         = (const float*)d_in[0];
  const float* edge_attr = (const float*)d_in[1];
  const int*   ei        = (const int*)d_in[2];   // [2][E]: row0=src, row1=dst
  const int*   batch     = (const int*)d_in[3];
  const float* Wa = (const float*)d_in[4];
  const float* ba = (const float*)d_in[5];
  const float* Wb = (const float*)d_in[6];
  const float* bb = (const float*)d_in[7];
  const float* W1 = (const float*)d_in[8];
  const float* b1 = (const float*)d_in[9];
  const float* W2 = (const float*)d_in[10];
  const float* b2 = (const float*)d_in[11];
  const float* W3 = (const float*)d_in[12];

  char* ws = (char*)d_ws;
  const size_t NB = (size_t)N_NODES * EMB * sizeof(float);               // 25.6 MB
  const size_t EB = (size_t)N_EDGES * EMB * sizeof(unsigned short);      // 128 MB
  float* bufA = (float*)ws;
  float* bufB = (float*)(ws + NB);
  unsigned short* eemb = (unsigned short*)(ws + 2 * NB);
  float* w1T = (float*)(ws + 2 * NB + EB);
  float* w2T = w1T + EMB * EMB;
  const size_t needed = 2 * NB + EB + (size_t)(EMB * EMB + 64 * EMB) * sizeof(float);
  if (ws_size < needed){
    fprintf(stderr, "kernel_launch: ws too small (%zu < %zu)\n", ws_size, needed);
    return;  // leaves d_out poisoned -> visible failure instead of corruption
  }

  transpose_w<<<96, 256, 0, stream>>>(W1, W2, w1T, w2T);

  // Step 1: embeddings
  gemm_bias<EMB, EMB, false><<<(N_NODES + 31) / 32, 256, 0, stream>>>(x, Wa, ba, bufA, N_NODES);
  gemm_bias<BOND, EMB, true><<<(N_EDGES + 31) / 32, 256, 0, stream>>>(edge_attr, Wb, bb, eemb, N_EDGES);

  // Step 2: two message-passing layers with residual (new = copy(old) + scatter-add)
  hipMemcpyAsync(bufB, bufA, NB, hipMemcpyDeviceToDevice, stream);
  msg_kernel<<<(N_EDGES + 7) / 8, 256, 0, stream>>>(bufA, eemb, ei, bufB);
  hipMemcpyAsync(bufA, bufB, NB, hipMemcpyDeviceToDevice, stream);
  msg_kernel<<<(N_EDGES + 7) / 8, 256, 0, stream>>>(bufB, eemb, ei, bufA);

  // Steps 3+4: fused MLP + global add pool
  hipMemsetAsync(d_out, 0, NGRAPH * sizeof(float), stream);
  mlp_pool<<<512, 256, 0, stream>>>(bufA, w1T, b1, w2T, b2, W3, batch, (float*)d_out);
}

// Round 2
// 908.790 us; speedup vs baseline: 2.7156x; 2.7156x over previous
//
#include <hip/hip_runtime.h>
#include <cstdio>
#include <cstdint>

#define N_NODES 50000
#define N_EDGES 500000
#define EMB 128
#define BOND 64
#define NGRAPH 256
#define NB_SCAN ((N_NODES + 255) / 256)   // 196 scan blocks

__device__ __forceinline__ unsigned short f2bf(float v){
  unsigned u = __float_as_uint(v);
  unsigned r = (u + 0x7fffu + ((u >> 16) & 1u)) >> 16;  // RNE
  return (unsigned short)r;
}
__device__ __forceinline__ float bf2f(unsigned short u){
  return __uint_as_float(((unsigned)u) << 16);
}

// out[r][c] = sum_k in[r][k] * W[c][k] + bias[c]
template<int K, int CO, bool BF16OUT>
__global__ __launch_bounds__(256) void gemm_bias(const float* __restrict__ in,
    const float* __restrict__ W, const float* __restrict__ bias,
    void* __restrict__ outp, long M)
{
  constexpr int KC = (K > 64) ? 64 : K;
  constexpr int NKC = K / KC;
  constexpr int LANES = CO / 4;
  constexpr int GROUPS = 256 / LANES;
  constexpr int RPB = GROUPS * 4;
  constexpr int ISTR = K + 1;
  __shared__ float wT[KC * CO];
  __shared__ float inT[RPB * ISTR];
  const int t = threadIdx.x;
  const int lc = t % LANES, g = t / LANES;
  const int c0 = lc * 4;
  const float4 bv = *(const float4*)(bias + c0);

  for (long r0 = (long)blockIdx.x * RPB; r0 < M; r0 += (long)gridDim.x * RPB){
    __syncthreads();
    for (int i = t; i < RPB * K; i += 256){
      int rr = i / K, k = i % K;
      long r = r0 + rr;
      inT[rr * ISTR + k] = (r < M) ? in[r * (long)K + k] : 0.f;
    }
    float acc[4][4];
    #pragma unroll
    for (int rr = 0; rr < 4; rr++){
      acc[rr][0] = bv.x; acc[rr][1] = bv.y; acc[rr][2] = bv.z; acc[rr][3] = bv.w;
    }
    for (int kc = 0; kc < NKC; kc++){
      __syncthreads();
      for (int i = t; i < KC * CO; i += 256){
        int c = i % CO, k = i / CO;
        wT[k * CO + c] = W[c * K + kc * KC + k];
      }
      __syncthreads();
      #pragma unroll 8
      for (int k = 0; k < KC; k++){
        float4 w = *(const float4*)&wT[k * CO + c0];
        #pragma unroll
        for (int rr = 0; rr < 4; rr++){
          float a = inT[(g * 4 + rr) * ISTR + kc * KC + k];
          acc[rr][0] = fmaf(a, w.x, acc[rr][0]);
          acc[rr][1] = fmaf(a, w.y, acc[rr][1]);
          acc[rr][2] = fmaf(a, w.z, acc[rr][2]);
          acc[rr][3] = fmaf(a, w.w, acc[rr][3]);
        }
      }
    }
    #pragma unroll
    for (int rr = 0; rr < 4; rr++){
      long r = r0 + g * 4 + rr;
      if (r < M){
        if (BF16OUT){
          ushort4 o;
          o.x = f2bf(acc[rr][0]); o.y = f2bf(acc[rr][1]);
          o.z = f2bf(acc[rr][2]); o.w = f2bf(acc[rr][3]);
          *(ushort4*)((unsigned short*)outp + r * CO + c0) = o;
        } else {
          float4 o = make_float4(acc[rr][0], acc[rr][1], acc[rr][2], acc[rr][3]);
          *(float4*)((float*)outp + r * CO + c0) = o;
        }
      }
    }
  }
}

// ---------------- CSR build (by dst) ----------------

__global__ __launch_bounds__(256) void count_deg(const int* __restrict__ ei,
                                                 int* __restrict__ deg)
{
  int e = blockIdx.x * 256 + threadIdx.x;
  if (e < N_EDGES) atomicAdd(&deg[ei[N_EDGES + e]], 1);
}

// S1: per-block sum of 256 degrees
__global__ __launch_bounds__(256) void scan_s1(const int* __restrict__ deg,
                                               int* __restrict__ blocksum)
{
  int i = blockIdx.x * 256 + threadIdx.x;
  int lane = threadIdx.x & 63, w = threadIdx.x >> 6;
  int v = (i < N_NODES) ? deg[i] : 0;
  #pragma unroll
  for (int o = 32; o > 0; o >>= 1) v += __shfl_down(v, o, 64);
  __shared__ int ws4[4];
  if (lane == 0) ws4[w] = v;
  __syncthreads();
  if (threadIdx.x == 0) blocksum[blockIdx.x] = ws4[0] + ws4[1] + ws4[2] + ws4[3];
}

// S2: single block exclusive-scans blocksum[NB_SCAN] -> blockoff; writes total to off[N_NODES]
__global__ __launch_bounds__(256) void scan_s2(const int* __restrict__ blocksum,
                                               int* __restrict__ blockoff,
                                               int* __restrict__ off)
{
  int t = threadIdx.x;
  int lane = t & 63, w = t >> 6;
  int v = (t < NB_SCAN) ? blocksum[t] : 0;
  int x = v;
  #pragma unroll
  for (int d = 1; d < 64; d <<= 1){
    int y = __shfl_up(x, d, 64);
    if (lane >= d) x += y;
  }
  __shared__ int wsum[4];
  if (lane == 63) wsum[w] = x;
  __syncthreads();
  int wo = 0;
  for (int j = 0; j < w; j++) wo += wsum[j];
  if (t < NB_SCAN) blockoff[t] = wo + x - v;
  if (t == 0) off[N_NODES] = wsum[0] + wsum[1] + wsum[2] + wsum[3];
}

// S3: per-block exclusive scan of 256 degrees + blockoff -> off[i] and fill[i]
__global__ __launch_bounds__(256) void scan_s3(const int* __restrict__ deg,
    const int* __restrict__ blockoff, int* __restrict__ off, int* __restrict__ fill)
{
  int i = blockIdx.x * 256 + threadIdx.x;
  int lane = threadIdx.x & 63, w = threadIdx.x >> 6;
  int v = (i < N_NODES) ? deg[i] : 0;
  int x = v;
  #pragma unroll
  for (int d = 1; d < 64; d <<= 1){
    int y = __shfl_up(x, d, 64);
    if (lane >= d) x += y;
  }
  __shared__ int wsum[4];
  if (lane == 63) wsum[w] = x;
  __syncthreads();
  int wo = 0;
  for (int j = 0; j < w; j++) wo += wsum[j];
  if (i < N_NODES){
    int excl = blockoff[blockIdx.x] + wo + x - v;
    off[i] = excl;
    fill[i] = excl;
  }
}

// scatter: cse[p] = {src, edge_id}; p = fill[dst]++
__global__ __launch_bounds__(256) void scatter_edges(const int* __restrict__ ei,
    int* __restrict__ fill, int2* __restrict__ cse)
{
  int e = blockIdx.x * 256 + threadIdx.x;
  if (e < N_EDGES){
    int dst = ei[N_EDGES + e];
    int p = atomicAdd(&fill[dst], 1);
    cse[p] = make_int2(ei[e], e);
  }
}

// ---------------- gather-based aggregation (residual fused) ----------------
// node_new[n] = node_old[n] + sum_{incoming e} node_old[src_e] * eemb[e]
// 32 lanes per node, 4 channels per lane. No atomics, coalesced writes.
__global__ __launch_bounds__(256) void agg_kernel(const float* __restrict__ node_old,
    const unsigned short* __restrict__ eemb, const int* __restrict__ off,
    const int2* __restrict__ cse, float* __restrict__ node_new)
{
  int n = blockIdx.x * 8 + (threadIdx.x >> 5);
  if (n >= N_NODES) return;
  int c0 = (threadIdx.x & 31) * 4;
  int s = off[n], e = off[n + 1];
  float4 acc = *(const float4*)(node_old + (long)n * EMB + c0);  // residual
  for (int i = s; i < e; i++){
    int2 se = cse[i];
    const float4 a = *(const float4*)(node_old + (long)se.x * EMB + c0);
    ushort4 eb = *(const ushort4*)(eemb + (long)se.y * EMB + c0);
    acc.x = fmaf(a.x, bf2f(eb.x), acc.x);
    acc.y = fmaf(a.y, bf2f(eb.y), acc.y);
    acc.z = fmaf(a.z, bf2f(eb.z), acc.z);
    acc.w = fmaf(a.w, bf2f(eb.w), acc.w);
  }
  *(float4*)(node_new + (long)n * EMB + c0) = acc;
}

// Pre-transpose MLP weights so mlp_pool reads them coalesced.
__global__ void transpose_w(const float* __restrict__ W1, const float* __restrict__ W2,
                            float* __restrict__ w1T, float* __restrict__ w2T)
{
  int i = blockIdx.x * 256 + threadIdx.x;
  if (i < EMB * EMB){
    int k = i >> 7, c = i & 127;
    w1T[i] = W1[c * EMB + k];
  } else {
    int j = i - EMB * EMB;
    if (j < 64 * EMB){
      int k = j >> 6, c = j & 63;
      w2T[j] = W2[c * EMB + k];
    }
  }
}

// Fused: relu -> W1 -> relu -> W2 -> relu -> W3 -> atomic pool into dg[256].
__global__ __launch_bounds__(256) void mlp_pool(const float* __restrict__ ne,
    const float* __restrict__ w1T, const float* __restrict__ b1,
    const float* __restrict__ w2T, const float* __restrict__ b2,
    const float* __restrict__ W3, const int* __restrict__ batch,
    float* __restrict__ dg)
{
  __shared__ float h0s[4][8 * EMB];
  __shared__ float h1s[4][8 * EMB];
  const int t = threadIdx.x;
  const int wid = t >> 6, l = t & 63;
  const long totalWaves = (long)gridDim.x * 4;
  const float b1a = b1[l], b1b = b1[64 + l];
  const float b2v = b2[l];
  const float w3v = W3[l];

  for (long n0 = ((long)blockIdx.x * 4 + wid) * 8; n0 < N_NODES; n0 += totalWaves * 8){
    int cnt = (int)((N_NODES - n0) < 8 ? (N_NODES - n0) : 8);
    #pragma unroll
    for (int j = 0; j < 8; j++){
      float v0 = 0.f, v1 = 0.f;
      if (j < cnt){
        v0 = fmaxf(ne[(n0 + j) * (long)EMB + l], 0.f);
        v1 = fmaxf(ne[(n0 + j) * (long)EMB + 64 + l], 0.f);
      }
      h0s[wid][j * EMB + l] = v0;
      h0s[wid][j * EMB + 64 + l] = v1;
    }
    float acc1a[8], acc1b[8];
    #pragma unroll
    for (int j = 0; j < 8; j++){ acc1a[j] = b1a; acc1b[j] = b1b; }
    for (int k = 0; k < EMB; k++){
      float wa = w1T[k * EMB + l];
      float wb = w1T[k * EMB + 64 + l];
      #pragma unroll
      for (int j = 0; j < 8; j++){
        float a = h0s[wid][j * EMB + k];
        acc1a[j] = fmaf(a, wa, acc1a[j]);
        acc1b[j] = fmaf(a, wb, acc1b[j]);
      }
    }
    #pragma unroll
    for (int j = 0; j < 8; j++){
      h1s[wid][j * EMB + l] = fmaxf(acc1a[j], 0.f);
      h1s[wid][j * EMB + 64 + l] = fmaxf(acc1b[j], 0.f);
    }
    float acc2[8];
    #pragma unroll
    for (int j = 0; j < 8; j++) acc2[j] = b2v;
    for (int k = 0; k < EMB; k++){
      float w2 = w2T[k * 64 + l];
      #pragma unroll
      for (int j = 0; j < 8; j++)
        acc2[j] = fmaf(h1s[wid][j * EMB + k], w2, acc2[j]);
    }
    #pragma unroll
    for (int j = 0; j < 8; j++){
      float ev = fmaxf(acc2[j], 0.f) * w3v;
      #pragma unroll
      for (int off = 32; off > 0; off >>= 1) ev += __shfl_down(ev, off, 64);
      if (l == 0 && j < cnt) atomicAdd(&dg[batch[n0 + j]], ev);
    }
  }
}

extern "C" void kernel_launch(void* const* d_in, const int* in_sizes, int n_in,
                              void* d_out, int out_size, void* d_ws, size_t ws_size,
                              hipStream_t stream)
{
  const float* x         = (const float*)d_in[0];
  const float* edge_attr = (const float*)d_in[1];
  const int*   ei        = (const int*)d_in[2];   // [2][E]: row0=src, row1=dst
  const int*   batch     = (const int*)d_in[3];
  const float* Wa = (const float*)d_in[4];
  const float* ba = (const float*)d_in[5];
  const float* Wb = (const float*)d_in[6];
  const float* bb = (const float*)d_in[7];
  const float* W1 = (const float*)d_in[8];
  const float* b1 = (const float*)d_in[9];
  const float* W2 = (const float*)d_in[10];
  const float* b2 = (const float*)d_in[11];
  const float* W3 = (const float*)d_in[12];

  char* ws = (char*)d_ws;
  size_t p = 0;
  auto alloc = [&](size_t bytes) -> char* {
    char* q = ws + p;
    p += (bytes + 255) & ~(size_t)255;
    return q;
  };
  float* bufA = (float*)alloc((size_t)N_NODES * EMB * sizeof(float));          // 25.6 MB
  float* bufB = (float*)alloc((size_t)N_NODES * EMB * sizeof(float));          // 25.6 MB
  unsigned short* eemb = (unsigned short*)alloc((size_t)N_EDGES * EMB * 2);    // 128 MB
  float* w1T = (float*)alloc(EMB * EMB * sizeof(float));
  float* w2T = (float*)alloc(64 * EMB * sizeof(float));
  int* deg  = (int*)alloc(N_NODES * sizeof(int));
  int* off  = (int*)alloc((N_NODES + 1) * sizeof(int));
  int* fill = (int*)alloc(N_NODES * sizeof(int));
  int* blocksum = (int*)alloc(NB_SCAN * sizeof(int));
  int* blockoff = (int*)alloc(NB_SCAN * sizeof(int));
  int2* cse = (int2*)alloc((size_t)N_EDGES * sizeof(int2));                    // 4 MB
  if (p > ws_size){
    fprintf(stderr, "kernel_launch: ws too small (%zu < %zu)\n", ws_size, p);
    return;
  }

  // CSR build
  hipMemsetAsync(deg, 0, N_NODES * sizeof(int), stream);
  count_deg<<<(N_EDGES + 255) / 256, 256, 0, stream>>>(ei, deg);
  scan_s1<<<NB_SCAN, 256, 0, stream>>>(deg, blocksum);
  scan_s2<<<1, 256, 0, stream>>>(blocksum, blockoff, off);
  scan_s3<<<NB_SCAN, 256, 0, stream>>>(deg, blockoff, off, fill);
  scatter_edges<<<(N_EDGES + 255) / 256, 256, 0, stream>>>(ei, fill, cse);

  // Embeddings
  transpose_w<<<96, 256, 0, stream>>>(W1, W2, w1T, w2T);
  gemm_bias<EMB, EMB, false><<<(N_NODES + 31) / 32, 256, 0, stream>>>(x, Wa, ba, bufA, N_NODES);
  gemm_bias<BOND, EMB, true><<<(N_EDGES + 31) / 32, 256, 0, stream>>>(edge_attr, Wb, bb, eemb, N_EDGES);

  // Two message-passing layers, gather-based, residual fused
  agg_kernel<<<(N_NODES + 7) / 8, 256, 0, stream>>>(bufA, eemb, off, cse, bufB);
  agg_kernel<<<(N_NODES + 7) / 8, 256, 0, stream>>>(bufB, eemb, off, cse, bufA);

  // Fused MLP + pool
  hipMemsetAsync(d_out, 0, NGRAPH * sizeof(float), stream);
  mlp_pool<<<512, 256, 0, stream>>>(bufA, w1T, b1, w2T, b2, W3, batch, (float*)d_out);
}

// Round 3
// 725.352 us; speedup vs baseline: 3.4023x; 1.2529x over previous
//
#include <hip/hip_runtime.h>
#include <cstdio>
#include <cstdint>

#define N_NODES 50000
#define N_EDGES 500000
#define EMB 128
#define BOND 64
#define NGRAPH 256
#define NB_SCAN ((N_NODES + 255) / 256)   // 196 scan blocks

typedef short bf16x8 __attribute__((ext_vector_type(8)));   // 8 bf16 (4 VGPRs)
typedef float f32x4  __attribute__((ext_vector_type(4)));

__device__ __forceinline__ unsigned short f2bf(float v){
  unsigned u = __float_as_uint(v);
  unsigned r = (u + 0x7fffu + ((u >> 16) & 1u)) >> 16;  // RNE
  return (unsigned short)r;
}
__device__ __forceinline__ float bf2f(unsigned short u){
  return __uint_as_float(((unsigned)u) << 16);
}

// ---------------- f32 GEMM (kept for node embedding, precision headroom) ----------------
// out[r][c] = sum_k in[r][k] * W[c][k] + bias[c]
template<int K, int CO, bool BF16OUT>
__global__ __launch_bounds__(256) void gemm_bias(const float* __restrict__ in,
    const float* __restrict__ W, const float* __restrict__ bias,
    void* __restrict__ outp, long M)
{
  constexpr int KC = (K > 64) ? 64 : K;
  constexpr int NKC = K / KC;
  constexpr int LANES = CO / 4;
  constexpr int GROUPS = 256 / LANES;
  constexpr int RPB = GROUPS * 4;
  constexpr int ISTR = K + 1;
  __shared__ float wT[KC * CO];
  __shared__ float inT[RPB * ISTR];
  const int t = threadIdx.x;
  const int lc = t % LANES, g = t / LANES;
  const int c0 = lc * 4;
  const float4 bv = *(const float4*)(bias + c0);

  for (long r0 = (long)blockIdx.x * RPB; r0 < M; r0 += (long)gridDim.x * RPB){
    __syncthreads();
    for (int i = t; i < RPB * K; i += 256){
      int rr = i / K, k = i % K;
      long r = r0 + rr;
      inT[rr * ISTR + k] = (r < M) ? in[r * (long)K + k] : 0.f;
    }
    float acc[4][4];
    #pragma unroll
    for (int rr = 0; rr < 4; rr++){
      acc[rr][0] = bv.x; acc[rr][1] = bv.y; acc[rr][2] = bv.z; acc[rr][3] = bv.w;
    }
    for (int kc = 0; kc < NKC; kc++){
      __syncthreads();
      for (int i = t; i < KC * CO; i += 256){
        int c = i % CO, k = i / CO;
        wT[k * CO + c] = W[c * K + kc * KC + k];
      }
      __syncthreads();
      #pragma unroll 8
      for (int k = 0; k < KC; k++){
        float4 w = *(const float4*)&wT[k * CO + c0];
        #pragma unroll
        for (int rr = 0; rr < 4; rr++){
          float a = inT[(g * 4 + rr) * ISTR + kc * KC + k];
          acc[rr][0] = fmaf(a, w.x, acc[rr][0]);
          acc[rr][1] = fmaf(a, w.y, acc[rr][1]);
          acc[rr][2] = fmaf(a, w.z, acc[rr][2]);
          acc[rr][3] = fmaf(a, w.w, acc[rr][3]);
        }
      }
    }
    #pragma unroll
    for (int rr = 0; rr < 4; rr++){
      long r = r0 + g * 4 + rr;
      if (r < M){
        if (BF16OUT){
          ushort4 o;
          o.x = f2bf(acc[rr][0]); o.y = f2bf(acc[rr][1]);
          o.z = f2bf(acc[rr][2]); o.w = f2bf(acc[rr][3]);
          *(ushort4*)((unsigned short*)outp + r * CO + c0) = o;
        } else {
          float4 o = make_float4(acc[rr][0], acc[rr][1], acc[rr][2], acc[rr][3]);
          *(float4*)((float*)outp + r * CO + c0) = o;
        }
      }
    }
  }
}

// ---------------- bf16 MFMA edge GEMM, writes eemb in CSR order ----------------
// eemb[pos[e]][c] = bf16( sum_k attr[e][k]*Wb[c][k] + bb[c] )
// Wave strip = 16 edge-rows x 128 cols. B-fragments (Wb^T) persistent in registers.
// Layouts (measured, learn_hip m89/m91): A[m=lane&15][k=(lane>>4)*8+j],
// B[k=(lane>>4)*8+j][n=lane&15], C: col=lane&15, row=(lane>>4)*4+reg.
__global__ __launch_bounds__(256) void edge_gemm_mfma(
    const float* __restrict__ attr, const float* __restrict__ Wb,
    const float* __restrict__ bb, const int* __restrict__ pos,
    unsigned short* __restrict__ eemb)
{
  const int t = threadIdx.x;
  const int wv = t >> 6;
  const int l  = t & 63;
  const int lm = l & 15;
  const int q  = l >> 4;
  union U8 { bf16x8 v; unsigned short s[8]; };

  bf16x8 bfrag[8][2];
  float bias[8];
  #pragma unroll
  for (int tn = 0; tn < 8; tn++){
    bias[tn] = bb[tn * 16 + lm];
    #pragma unroll
    for (int h = 0; h < 2; h++){
      const float* wp = Wb + (tn * 16 + lm) * BOND + h * 32 + q * 8;
      float4 w0 = *(const float4*)wp;
      float4 w1 = *(const float4*)(wp + 4);
      U8 u;
      u.s[0] = f2bf(w0.x); u.s[1] = f2bf(w0.y); u.s[2] = f2bf(w0.z); u.s[3] = f2bf(w0.w);
      u.s[4] = f2bf(w1.x); u.s[5] = f2bf(w1.y); u.s[6] = f2bf(w1.z); u.s[7] = f2bf(w1.w);
      bfrag[tn][h] = u.v;
    }
  }

  const long stride = (long)gridDim.x * 4 * 16;
  for (long r0 = ((long)blockIdx.x * 4 + wv) * 16; r0 < N_EDGES; r0 += stride){
    long rm = r0 + lm;
    bool valid = rm < N_EDGES;
    bf16x8 afrag[2];
    #pragma unroll
    for (int h = 0; h < 2; h++){
      float4 a0 = make_float4(0.f,0.f,0.f,0.f), a1 = a0;
      if (valid){
        const float* ap = attr + rm * (long)BOND + h * 32 + q * 8;
        a0 = *(const float4*)ap;
        a1 = *(const float4*)(ap + 4);
      }
      U8 u;
      u.s[0] = f2bf(a0.x); u.s[1] = f2bf(a0.y); u.s[2] = f2bf(a0.z); u.s[3] = f2bf(a0.w);
      u.s[4] = f2bf(a1.x); u.s[5] = f2bf(a1.y); u.s[6] = f2bf(a1.z); u.s[7] = f2bf(a1.w);
      afrag[h] = u.v;
    }
    long pr[4];
    #pragma unroll
    for (int i = 0; i < 4; i++){
      long r = r0 + q * 4 + i;
      pr[i] = (r < N_EDGES) ? (long)pos[r] : -1;
    }
    #pragma unroll
    for (int tn = 0; tn < 8; tn++){
      f32x4 acc = {0.f, 0.f, 0.f, 0.f};
      acc = __builtin_amdgcn_mfma_f32_16x16x32_bf16(afrag[0], bfrag[tn][0], acc, 0, 0, 0);
      acc = __builtin_amdgcn_mfma_f32_16x16x32_bf16(afrag[1], bfrag[tn][1], acc, 0, 0, 0);
      #pragma unroll
      for (int i = 0; i < 4; i++){
        if (pr[i] >= 0)
          eemb[pr[i] * EMB + tn * 16 + lm] = f2bf(acc[i] + bias[tn]);
      }
    }
  }
}

// ---------------- CSR build (by dst) ----------------

__global__ __launch_bounds__(256) void count_deg(const int* __restrict__ ei,
                                                 int* __restrict__ deg)
{
  int e = blockIdx.x * 256 + threadIdx.x;
  if (e < N_EDGES) atomicAdd(&deg[ei[N_EDGES + e]], 1);
}

__global__ __launch_bounds__(256) void scan_s1(const int* __restrict__ deg,
                                               int* __restrict__ blocksum)
{
  int i = blockIdx.x * 256 + threadIdx.x;
  int lane = threadIdx.x & 63, w = threadIdx.x >> 6;
  int v = (i < N_NODES) ? deg[i] : 0;
  #pragma unroll
  for (int o = 32; o > 0; o >>= 1) v += __shfl_down(v, o, 64);
  __shared__ int ws4[4];
  if (lane == 0) ws4[w] = v;
  __syncthreads();
  if (threadIdx.x == 0) blocksum[blockIdx.x] = ws4[0] + ws4[1] + ws4[2] + ws4[3];
}

__global__ __launch_bounds__(256) void scan_s2(const int* __restrict__ blocksum,
                                               int* __restrict__ blockoff,
                                               int* __restrict__ off)
{
  int t = threadIdx.x;
  int lane = t & 63, w = t >> 6;
  int v = (t < NB_SCAN) ? blocksum[t] : 0;
  int x = v;
  #pragma unroll
  for (int d = 1; d < 64; d <<= 1){
    int y = __shfl_up(x, d, 64);
    if (lane >= d) x += y;
  }
  __shared__ int wsum[4];
  if (lane == 63) wsum[w] = x;
  __syncthreads();
  int wo = 0;
  for (int j = 0; j < w; j++) wo += wsum[j];
  if (t < NB_SCAN) blockoff[t] = wo + x - v;
  if (t == 0) off[N_NODES] = wsum[0] + wsum[1] + wsum[2] + wsum[3];
}

__global__ __launch_bounds__(256) void scan_s3(const int* __restrict__ deg,
    const int* __restrict__ blockoff, int* __restrict__ off, int* __restrict__ fill)
{
  int i = blockIdx.x * 256 + threadIdx.x;
  int lane = threadIdx.x & 63, w = threadIdx.x >> 6;
  int v = (i < N_NODES) ? deg[i] : 0;
  int x = v;
  #pragma unroll
  for (int d = 1; d < 64; d <<= 1){
    int y = __shfl_up(x, d, 64);
    if (lane >= d) x += y;
  }
  __shared__ int wsum[4];
  if (lane == 63) wsum[w] = x;
  __syncthreads();
  int wo = 0;
  for (int j = 0; j < w; j++) wo += wsum[j];
  if (i < N_NODES){
    int excl = blockoff[blockIdx.x] + wo + x - v;
    off[i] = excl;
    fill[i] = excl;
  }
}

// csrc[p] = src, pos[e] = p  (p = fill[dst]++)
__global__ __launch_bounds__(256) void scatter_edges(const int* __restrict__ ei,
    int* __restrict__ fill, int* __restrict__ csrc, int* __restrict__ pos)
{
  int e = blockIdx.x * 256 + threadIdx.x;
  if (e < N_EDGES){
    int dst = ei[N_EDGES + e];
    int p = atomicAdd(&fill[dst], 1);
    csrc[p] = ei[e];
    pos[e] = p;
  }
}

// ---------------- gather aggregation (residual fused, eemb CSR-ordered) ----------------
__global__ __launch_bounds__(256) void agg_kernel(const float* __restrict__ node_old,
    const unsigned short* __restrict__ eemb, const int* __restrict__ off,
    const int* __restrict__ csrc, float* __restrict__ node_new)
{
  int n = blockIdx.x * 8 + (threadIdx.x >> 5);
  if (n >= N_NODES) return;
  int c0 = (threadIdx.x & 31) * 4;
  int s = off[n], e = off[n + 1];
  float4 acc = *(const float4*)(node_old + (long)n * EMB + c0);  // residual
  for (int i = s; i < e; i++){
    int src = csrc[i];
    const float4 a = *(const float4*)(node_old + (long)src * EMB + c0);
    ushort4 eb = *(const ushort4*)(eemb + (long)i * EMB + c0);
    acc.x = fmaf(a.x, bf2f(eb.x), acc.x);
    acc.y = fmaf(a.y, bf2f(eb.y), acc.y);
    acc.z = fmaf(a.z, bf2f(eb.z), acc.z);
    acc.w = fmaf(a.w, bf2f(eb.w), acc.w);
  }
  *(float4*)(node_new + (long)n * EMB + c0) = acc;
}

// ---------------- MLP weight pre-transpose ----------------
__global__ void transpose_w(const float* __restrict__ W1, const float* __restrict__ W2,
                            float* __restrict__ w1T, float* __restrict__ w2T)
{
  int i = blockIdx.x * 256 + threadIdx.x;
  if (i < EMB * EMB){
    int k = i >> 7, c = i & 127;
    w1T[i] = W1[c * EMB + k];
  } else {
    int j = i - EMB * EMB;
    if (j < 64 * EMB){
      int k = j >> 6, c = j & 63;
      w2T[j] = W2[c * EMB + k];
    }
  }
}

// ---------------- fused MLP + pool ----------------
__global__ __launch_bounds__(256) void mlp_pool(const float* __restrict__ ne,
    const float* __restrict__ w1T, const float* __restrict__ b1,
    const float* __restrict__ w2T, const float* __restrict__ b2,
    const float* __restrict__ W3, const int* __restrict__ batch,
    float* __restrict__ dg)
{
  __shared__ float h0s[4][8 * EMB];
  __shared__ float h1s[4][8 * EMB];
  const int t = threadIdx.x;
  const int wid = t >> 6, l = t & 63;
  const long totalWaves = (long)gridDim.x * 4;
  const float b1a = b1[l], b1b = b1[64 + l];
  const float b2v = b2[l];
  const float w3v = W3[l];

  for (long n0 = ((long)blockIdx.x * 4 + wid) * 8; n0 < N_NODES; n0 += totalWaves * 8){
    int cnt = (int)((N_NODES - n0) < 8 ? (N_NODES - n0) : 8);
    #pragma unroll
    for (int j = 0; j < 8; j++){
      float v0 = 0.f, v1 = 0.f;
      if (j < cnt){
        v0 = fmaxf(ne[(n0 + j) * (long)EMB + l], 0.f);
        v1 = fmaxf(ne[(n0 + j) * (long)EMB + 64 + l], 0.f);
      }
      h0s[wid][j * EMB + l] = v0;
      h0s[wid][j * EMB + 64 + l] = v1;
    }
    float acc1a[8], acc1b[8];
    #pragma unroll
    for (int j = 0; j < 8; j++){ acc1a[j] = b1a; acc1b[j] = b1b; }
    for (int k = 0; k < EMB; k++){
      float wa = w1T[k * EMB + l];
      float wb = w1T[k * EMB + 64 + l];
      #pragma unroll
      for (int j = 0; j < 8; j++){
        float a = h0s[wid][j * EMB + k];
        acc1a[j] = fmaf(a, wa, acc1a[j]);
        acc1b[j] = fmaf(a, wb, acc1b[j]);
      }
    }
    #pragma unroll
    for (int j = 0; j < 8; j++){
      h1s[wid][j * EMB + l] = fmaxf(acc1a[j], 0.f);
      h1s[wid][j * EMB + 64 + l] = fmaxf(acc1b[j], 0.f);
    }
    float acc2[8];
    #pragma unroll
    for (int j = 0; j < 8; j++) acc2[j] = b2v;
    for (int k = 0; k < EMB; k++){
      float w2 = w2T[k * 64 + l];
      #pragma unroll
      for (int j = 0; j < 8; j++)
        acc2[j] = fmaf(h1s[wid][j * EMB + k], w2, acc2[j]);
    }
    #pragma unroll
    for (int j = 0; j < 8; j++){
      float ev = fmaxf(acc2[j], 0.f) * w3v;
      #pragma unroll
      for (int off = 32; off > 0; off >>= 1) ev += __shfl_down(ev, off, 64);
      if (l == 0 && j < cnt) atomicAdd(&dg[batch[n0 + j]], ev);
    }
  }
}

extern "C" void kernel_launch(void* const* d_in, const int* in_sizes, int n_in,
                              void* d_out, int out_size, void* d_ws, size_t ws_size,
                              hipStream_t stream)
{
  const float* x         = (const float*)d_in[0];
  const float* edge_attr = (const float*)d_in[1];
  const int*   ei        = (const int*)d_in[2];   // [2][E]: row0=src, row1=dst
  const int*   batch     = (const int*)d_in[3];
  const float* Wa = (const float*)d_in[4];
  const float* ba = (const float*)d_in[5];
  const float* Wb = (const float*)d_in[6];
  const float* bb = (const float*)d_in[7];
  const float* W1 = (const float*)d_in[8];
  const float* b1 = (const float*)d_in[9];
  const float* W2 = (const float*)d_in[10];
  const float* b2 = (const float*)d_in[11];
  const float* W3 = (const float*)d_in[12];

  char* ws = (char*)d_ws;
  size_t p = 0;
  auto alloc = [&](size_t bytes) -> char* {
    char* q = ws + p;
    p += (bytes + 255) & ~(size_t)255;
    return q;
  };
  float* bufA = (float*)alloc((size_t)N_NODES * EMB * sizeof(float));          // 25.6 MB
  float* bufB = (float*)alloc((size_t)N_NODES * EMB * sizeof(float));          // 25.6 MB
  unsigned short* eemb = (unsigned short*)alloc((size_t)N_EDGES * EMB * 2);    // 128 MB
  float* w1T = (float*)alloc(EMB * EMB * sizeof(float));
  float* w2T = (float*)alloc(64 * EMB * sizeof(float));
  int* deg  = (int*)alloc(N_NODES * sizeof(int));
  int* off  = (int*)alloc((N_NODES + 1) * sizeof(int));
  int* fill = (int*)alloc(N_NODES * sizeof(int));
  int* blocksum = (int*)alloc(NB_SCAN * sizeof(int));
  int* blockoff = (int*)alloc(NB_SCAN * sizeof(int));
  int* csrc = (int*)alloc((size_t)N_EDGES * sizeof(int));                      // 2 MB
  int* pos  = (int*)alloc((size_t)N_EDGES * sizeof(int));                      // 2 MB
  if (p > ws_size){
    fprintf(stderr, "kernel_launch: ws too small (%zu < %zu)\n", ws_size, p);
    return;
  }

  // CSR build
  hipMemsetAsync(deg, 0, N_NODES * sizeof(int), stream);
  count_deg<<<(N_EDGES + 255) / 256, 256, 0, stream>>>(ei, deg);
  scan_s1<<<NB_SCAN, 256, 0, stream>>>(deg, blocksum);
  scan_s2<<<1, 256, 0, stream>>>(blocksum, blockoff, off);
  scan_s3<<<NB_SCAN, 256, 0, stream>>>(deg, blockoff, off, fill);
  scatter_edges<<<(N_EDGES + 255) / 256, 256, 0, stream>>>(ei, fill, csrc, pos);

  // Embeddings: node (f32 VALU), edge (bf16 MFMA, CSR-ordered output)
  transpose_w<<<96, 256, 0, stream>>>(W1, W2, w1T, w2T);
  gemm_bias<EMB, EMB, false><<<(N_NODES + 31) / 32, 256, 0, stream>>>(x, Wa, ba, bufA, N_NODES);
  edge_gemm_mfma<<<1024, 256, 0, stream>>>(edge_attr, Wb, bb, pos, eemb);

  // Two message-passing layers, gather-based, residual fused
  agg_kernel<<<(N_NODES + 7) / 8, 256, 0, stream>>>(bufA, eemb, off, csrc, bufB);
  agg_kernel<<<(N_NODES + 7) / 8, 256, 0, stream>>>(bufB, eemb, off, csrc, bufA);

  // Fused MLP + pool
  hipMemsetAsync(d_out, 0, NGRAPH * sizeof(float), stream);
  mlp_pool<<<512, 256, 0, stream>>>(bufA, w1T, b1, w2T, b2, W3, batch, (float*)d_out);
}

// Round 4
// 631.167 us; speedup vs baseline: 3.9100x; 1.1492x over previous
//
#include <hip/hip_runtime.h>
#include <cstdio>
#include <cstdint>

#define N_NODES 50000
#define N_EDGES 500000
#define EMB 128
#define BOND 64
#define NGRAPH 256
#define NB_SCAN ((N_NODES + 255) / 256)   // 196 scan blocks
#define NSTRIP (N_NODES / 16)             // 3125 exact 16-node strips

typedef short bf16x8 __attribute__((ext_vector_type(8)));   // 8 bf16 (4 VGPRs)
typedef float f32x4  __attribute__((ext_vector_type(4)));

__device__ __forceinline__ unsigned short f2bf(float v){
  unsigned u = __float_as_uint(v);
  unsigned r = (u + 0x7fffu + ((u >> 16) & 1u)) >> 16;  // RNE
  return (unsigned short)r;
}
__device__ __forceinline__ float bf2f(unsigned short u){
  return __uint_as_float(((unsigned)u) << 16);
}

// ---------------- f32 GEMM (node embedding, precision headroom) ----------------
template<int K, int CO, bool BF16OUT>
__global__ __launch_bounds__(256) void gemm_bias(const float* __restrict__ in,
    const float* __restrict__ W, const float* __restrict__ bias,
    void* __restrict__ outp, long M)
{
  constexpr int KC = (K > 64) ? 64 : K;
  constexpr int NKC = K / KC;
  constexpr int LANES = CO / 4;
  constexpr int GROUPS = 256 / LANES;
  constexpr int RPB = GROUPS * 4;
  constexpr int ISTR = K + 1;
  __shared__ float wT[KC * CO];
  __shared__ float inT[RPB * ISTR];
  const int t = threadIdx.x;
  const int lc = t % LANES, g = t / LANES;
  const int c0 = lc * 4;
  const float4 bv = *(const float4*)(bias + c0);

  for (long r0 = (long)blockIdx.x * RPB; r0 < M; r0 += (long)gridDim.x * RPB){
    __syncthreads();
    for (int i = t; i < RPB * K; i += 256){
      int rr = i / K, k = i % K;
      long r = r0 + rr;
      inT[rr * ISTR + k] = (r < M) ? in[r * (long)K + k] : 0.f;
    }
    float acc[4][4];
    #pragma unroll
    for (int rr = 0; rr < 4; rr++){
      acc[rr][0] = bv.x; acc[rr][1] = bv.y; acc[rr][2] = bv.z; acc[rr][3] = bv.w;
    }
    for (int kc = 0; kc < NKC; kc++){
      __syncthreads();
      for (int i = t; i < KC * CO; i += 256){
        int c = i % CO, k = i / CO;
        wT[k * CO + c] = W[c * K + kc * KC + k];
      }
      __syncthreads();
      #pragma unroll 8
      for (int k = 0; k < KC; k++){
        float4 w = *(const float4*)&wT[k * CO + c0];
        #pragma unroll
        for (int rr = 0; rr < 4; rr++){
          float a = inT[(g * 4 + rr) * ISTR + kc * KC + k];
          acc[rr][0] = fmaf(a, w.x, acc[rr][0]);
          acc[rr][1] = fmaf(a, w.y, acc[rr][1]);
          acc[rr][2] = fmaf(a, w.z, acc[rr][2]);
          acc[rr][3] = fmaf(a, w.w, acc[rr][3]);
        }
      }
    }
    #pragma unroll
    for (int rr = 0; rr < 4; rr++){
      long r = r0 + g * 4 + rr;
      if (r < M){
        if (BF16OUT){
          ushort4 o;
          o.x = f2bf(acc[rr][0]); o.y = f2bf(acc[rr][1]);
          o.z = f2bf(acc[rr][2]); o.w = f2bf(acc[rr][3]);
          *(ushort4*)((unsigned short*)outp + r * CO + c0) = o;
        } else {
          float4 o = make_float4(acc[rr][0], acc[rr][1], acc[rr][2], acc[rr][3]);
          *(float4*)((float*)outp + r * CO + c0) = o;
        }
      }
    }
  }
}

// ---------------- bf16 MFMA edge GEMM, writes eemb in CSR order ----------------
__global__ __launch_bounds__(256) void edge_gemm_mfma(
    const float* __restrict__ attr, const float* __restrict__ Wb,
    const float* __restrict__ bb, const int* __restrict__ pos,
    unsigned short* __restrict__ eemb)
{
  const int t = threadIdx.x;
  const int wv = t >> 6;
  const int l  = t & 63;
  const int lm = l & 15;
  const int q  = l >> 4;
  union U8 { bf16x8 v; unsigned short s[8]; };

  bf16x8 bfrag[8][2];
  float bias[8];
  #pragma unroll
  for (int tn = 0; tn < 8; tn++){
    bias[tn] = bb[tn * 16 + lm];
    #pragma unroll
    for (int h = 0; h < 2; h++){
      const float* wp = Wb + (tn * 16 + lm) * BOND + h * 32 + q * 8;
      float4 w0 = *(const float4*)wp;
      float4 w1 = *(const float4*)(wp + 4);
      U8 u;
      u.s[0] = f2bf(w0.x); u.s[1] = f2bf(w0.y); u.s[2] = f2bf(w0.z); u.s[3] = f2bf(w0.w);
      u.s[4] = f2bf(w1.x); u.s[5] = f2bf(w1.y); u.s[6] = f2bf(w1.z); u.s[7] = f2bf(w1.w);
      bfrag[tn][h] = u.v;
    }
  }

  const long stride = (long)gridDim.x * 4 * 16;
  for (long r0 = ((long)blockIdx.x * 4 + wv) * 16; r0 < N_EDGES; r0 += stride){
    long rm = r0 + lm;
    bool valid = rm < N_EDGES;
    bf16x8 afrag[2];
    #pragma unroll
    for (int h = 0; h < 2; h++){
      float4 a0 = make_float4(0.f,0.f,0.f,0.f), a1 = a0;
      if (valid){
        const float* ap = attr + rm * (long)BOND + h * 32 + q * 8;
        a0 = *(const float4*)ap;
        a1 = *(const float4*)(ap + 4);
      }
      U8 u;
      u.s[0] = f2bf(a0.x); u.s[1] = f2bf(a0.y); u.s[2] = f2bf(a0.z); u.s[3] = f2bf(a0.w);
      u.s[4] = f2bf(a1.x); u.s[5] = f2bf(a1.y); u.s[6] = f2bf(a1.z); u.s[7] = f2bf(a1.w);
      afrag[h] = u.v;
    }
    long pr[4];
    #pragma unroll
    for (int i = 0; i < 4; i++){
      long r = r0 + q * 4 + i;
      pr[i] = (r < N_EDGES) ? (long)pos[r] : -1;
    }
    #pragma unroll
    for (int tn = 0; tn < 8; tn++){
      f32x4 acc = {0.f, 0.f, 0.f, 0.f};
      acc = __builtin_amdgcn_mfma_f32_16x16x32_bf16(afrag[0], bfrag[tn][0], acc, 0, 0, 0);
      acc = __builtin_amdgcn_mfma_f32_16x16x32_bf16(afrag[1], bfrag[tn][1], acc, 0, 0, 0);
      #pragma unroll
      for (int i = 0; i < 4; i++){
        if (pr[i] >= 0)
          eemb[pr[i] * EMB + tn * 16 + lm] = f2bf(acc[i] + bias[tn]);
      }
    }
  }
}

// ---------------- CSR build (by dst) ----------------

__global__ __launch_bounds__(256) void count_deg(const int* __restrict__ ei,
                                                 int* __restrict__ deg)
{
  int e = blockIdx.x * 256 + threadIdx.x;
  if (e < N_EDGES) atomicAdd(&deg[ei[N_EDGES + e]], 1);
}

__global__ __launch_bounds__(256) void scan_s1(const int* __restrict__ deg,
                                               int* __restrict__ blocksum)
{
  int i = blockIdx.x * 256 + threadIdx.x;
  int lane = threadIdx.x & 63, w = threadIdx.x >> 6;
  int v = (i < N_NODES) ? deg[i] : 0;
  #pragma unroll
  for (int o = 32; o > 0; o >>= 1) v += __shfl_down(v, o, 64);
  __shared__ int ws4[4];
  if (lane == 0) ws4[w] = v;
  __syncthreads();
  if (threadIdx.x == 0) blocksum[blockIdx.x] = ws4[0] + ws4[1] + ws4[2] + ws4[3];
}

__global__ __launch_bounds__(256) void scan_s2(const int* __restrict__ blocksum,
                                               int* __restrict__ blockoff,
                                               int* __restrict__ off)
{
  int t = threadIdx.x;
  int lane = t & 63, w = t >> 6;
  int v = (t < NB_SCAN) ? blocksum[t] : 0;
  int x = v;
  #pragma unroll
  for (int d = 1; d < 64; d <<= 1){
    int y = __shfl_up(x, d, 64);
    if (lane >= d) x += y;
  }
  __shared__ int wsum[4];
  if (lane == 63) wsum[w] = x;
  __syncthreads();
  int wo = 0;
  for (int j = 0; j < w; j++) wo += wsum[j];
  if (t < NB_SCAN) blockoff[t] = wo + x - v;
  if (t == 0) off[N_NODES] = wsum[0] + wsum[1] + wsum[2] + wsum[3];
}

__global__ __launch_bounds__(256) void scan_s3(const int* __restrict__ deg,
    const int* __restrict__ blockoff, int* __restrict__ off, int* __restrict__ fill)
{
  int i = blockIdx.x * 256 + threadIdx.x;
  int lane = threadIdx.x & 63, w = threadIdx.x >> 6;
  int v = (i < N_NODES) ? deg[i] : 0;
  int x = v;
  #pragma unroll
  for (int d = 1; d < 64; d <<= 1){
    int y = __shfl_up(x, d, 64);
    if (lane >= d) x += y;
  }
  __shared__ int wsum[4];
  if (lane == 63) wsum[w] = x;
  __syncthreads();
  int wo = 0;
  for (int j = 0; j < w; j++) wo += wsum[j];
  if (i < N_NODES){
    int excl = blockoff[blockIdx.x] + wo + x - v;
    off[i] = excl;
    fill[i] = excl;
  }
}

__global__ __launch_bounds__(256) void scatter_edges(const int* __restrict__ ei,
    int* __restrict__ fill, int* __restrict__ csrc, int* __restrict__ pos)
{
  int e = blockIdx.x * 256 + threadIdx.x;
  if (e < N_EDGES){
    int dst = ei[N_EDGES + e];
    int p = atomicAdd(&fill[dst], 1);
    csrc[p] = ei[e];
    pos[e] = p;
  }
}

// ---------------- gather aggregation (residual fused, eemb CSR-ordered) ----------------
__global__ __launch_bounds__(256) void agg_kernel(const float* __restrict__ node_old,
    const unsigned short* __restrict__ eemb, const int* __restrict__ off,
    const int* __restrict__ csrc, float* __restrict__ node_new)
{
  int n = blockIdx.x * 8 + (threadIdx.x >> 5);
  if (n >= N_NODES) return;
  int c0 = (threadIdx.x & 31) * 4;
  int s = off[n], e = off[n + 1];
  float4 acc = *(const float4*)(node_old + (long)n * EMB + c0);  // residual
  for (int i = s; i < e; i++){
    int src = csrc[i];
    const float4 a = *(const float4*)(node_old + (long)src * EMB + c0);
    ushort4 eb = *(const ushort4*)(eemb + (long)i * EMB + c0);
    acc.x = fmaf(a.x, bf2f(eb.x), acc.x);
    acc.y = fmaf(a.y, bf2f(eb.y), acc.y);
    acc.z = fmaf(a.z, bf2f(eb.z), acc.z);
    acc.w = fmaf(a.w, bf2f(eb.w), acc.w);
  }
  *(float4*)(node_new + (long)n * EMB + c0) = acc;
}

// ---------------- MLP weight prep: fragment-linear bf16 ----------------
// w1bf[((tn*4+kc)*64 + l)*8 + j] = bf16(W1[tn*16+lm][kc*32+q*8+j]), l=q*16+lm
// w2bf likewise over [64][128].
__global__ void prep_mlp(const float* __restrict__ W1, const float* __restrict__ W2,
                         unsigned short* __restrict__ w1bf, unsigned short* __restrict__ w2bf)
{
  int i = blockIdx.x * 256 + threadIdx.x;
  if (i < 16384){
    int j = i & 7, lb = (i >> 3) & 63, kc = (i >> 9) & 3, tn = i >> 11;
    int lm = lb & 15, q = lb >> 4;
    w1bf[i] = f2bf(W1[(tn * 16 + lm) * EMB + kc * 32 + q * 8 + j]);
  } else if (i < 16384 + 8192){
    int i2 = i - 16384;
    int j = i2 & 7, lb = (i2 >> 3) & 63, kc = (i2 >> 9) & 3, tc = i2 >> 11;
    int lm = lb & 15, q = lb >> 4;
    w2bf[i2] = f2bf(W2[(tc * 16 + lm) * EMB + kc * 32 + q * 8 + j]);
  }
}

// ---------------- fused MFMA MLP + pool ----------------
// Per wave: 16-node strip. relu->W1 (32 MFMA) -> relu -> LDS layout flip ->
// W2 (16 MFMA) -> relu -> W3 dot + shfl reduce -> atomic pool.
// Layouts (verified via edge_gemm_mfma): A[m=lane&15][k=q*8+j],
// B[k=q*8+j][n=lane&15], C: col=lane&15, row=q*4+reg.
__global__ __launch_bounds__(256) void mlp_mfma_pool(const float* __restrict__ ne,
    const unsigned short* __restrict__ w1bf, const unsigned short* __restrict__ w2bf,
    const float* __restrict__ b1, const float* __restrict__ b2,
    const float* __restrict__ W3, const int* __restrict__ batch,
    float* __restrict__ dg)
{
  __shared__ float h1s[4][16 * 132];   // per-wave, stride 132 dwords (2-way conflicts only)
  const int t = threadIdx.x;
  const int wv = t >> 6, l = t & 63;
  const int lm = l & 15, q = l >> 4;
  union U8 { bf16x8 v; unsigned short s[8]; };

  int strip = blockIdx.x * 4 + wv;
  if (strip >= NSTRIP) return;
  const long n0 = (long)strip * 16;

  float b1v[8], b2v[4], w3v[4];
  #pragma unroll
  for (int tn = 0; tn < 8; tn++) b1v[tn] = b1[tn * 16 + lm];
  #pragma unroll
  for (int tc = 0; tc < 4; tc++){ b2v[tc] = b2[tc * 16 + lm]; w3v[tc] = W3[tc * 16 + lm]; }

  // A-fragments of relu(ne) : A[m=lm][k=kc*32+q*8+j]
  bf16x8 a1[4];
  #pragma unroll
  for (int kc = 0; kc < 4; kc++){
    const float* ap = ne + (n0 + lm) * EMB + kc * 32 + q * 8;
    float4 x0 = *(const float4*)ap;
    float4 x1 = *(const float4*)(ap + 4);
    U8 u;
    u.s[0] = f2bf(fmaxf(x0.x, 0.f)); u.s[1] = f2bf(fmaxf(x0.y, 0.f));
    u.s[2] = f2bf(fmaxf(x0.z, 0.f)); u.s[3] = f2bf(fmaxf(x0.w, 0.f));
    u.s[4] = f2bf(fmaxf(x1.x, 0.f)); u.s[5] = f2bf(fmaxf(x1.y, 0.f));
    u.s[6] = f2bf(fmaxf(x1.z, 0.f)); u.s[7] = f2bf(fmaxf(x1.w, 0.f));
    a1[kc] = u.v;
  }

  // Layer 1: out1[m][n] = sum_k A[m][k] * W1[n][k], n = tn*16+lm
  f32x4 acc1[8];
  #pragma unroll
  for (int tn = 0; tn < 8; tn++) acc1[tn] = (f32x4){b1v[tn], b1v[tn], b1v[tn], b1v[tn]};
  #pragma unroll
  for (int kc = 0; kc < 4; kc++){
    #pragma unroll
    for (int tn = 0; tn < 8; tn++){
      bf16x8 bf = *(const bf16x8*)(w1bf + (size_t)((tn * 4 + kc) * 64 + l) * 8);
      acc1[tn] = __builtin_amdgcn_mfma_f32_16x16x32_bf16(a1[kc], bf, acc1[tn], 0, 0, 0);
    }
  }

  // relu -> LDS (C layout -> row-major h1[m][k]) -> A-fragments for layer 2
  float* h1 = h1s[wv];
  #pragma unroll
  for (int tn = 0; tn < 8; tn++)
    #pragma unroll
    for (int i = 0; i < 4; i++)
      h1[(q * 4 + i) * 132 + tn * 16 + lm] = fmaxf(acc1[tn][i], 0.f);
  // wave-internal RAW on LDS: compiler inserts lgkmcnt wait; no barrier needed (per-wave buffer)
  bf16x8 a2[4];
  #pragma unroll
  for (int kc = 0; kc < 4; kc++){
    const float* hp = h1 + lm * 132 + kc * 32 + q * 8;
    float4 x0 = *(const float4*)hp;
    float4 x1 = *(const float4*)(hp + 4);
    U8 u;
    u.s[0] = f2bf(x0.x); u.s[1] = f2bf(x0.y); u.s[2] = f2bf(x0.z); u.s[3] = f2bf(x0.w);
    u.s[4] = f2bf(x1.x); u.s[5] = f2bf(x1.y); u.s[6] = f2bf(x1.z); u.s[7] = f2bf(x1.w);
    a2[kc] = u.v;
  }

  // Layer 2: 64 outputs = 4 col tiles
  f32x4 acc2[4];
  #pragma unroll
  for (int tc = 0; tc < 4; tc++) acc2[tc] = (f32x4){b2v[tc], b2v[tc], b2v[tc], b2v[tc]};
  #pragma unroll
  for (int kc = 0; kc < 4; kc++){
    #pragma unroll
    for (int tc = 0; tc < 4; tc++){
      bf16x8 bf = *(const bf16x8*)(w2bf + (size_t)((tc * 4 + kc) * 64 + l) * 8);
      acc2[tc] = __builtin_amdgcn_mfma_f32_16x16x32_bf16(a2[kc], bf, acc2[tc], 0, 0, 0);
    }
  }

  // Layer 3: energy[m] = sum_n relu(out2[m][n]) * W3[n]; reduce over lm (16 lanes)
  float e4[4];
  #pragma unroll
  for (int i = 0; i < 4; i++){
    float s = 0.f;
    #pragma unroll
    for (int tc = 0; tc < 4; tc++) s = fmaf(fmaxf(acc2[tc][i], 0.f), w3v[tc], s);
    e4[i] = s;
  }
  #pragma unroll
  for (int m = 1; m < 16; m <<= 1)
    #pragma unroll
    for (int i = 0; i < 4; i++) e4[i] += __shfl_xor(e4[i], m, 64);
  if (lm == 0){
    #pragma unroll
    for (int i = 0; i < 4; i++){
      int node = (int)n0 + q * 4 + i;
      atomicAdd(&dg[batch[node]], e4[i]);
    }
  }
}

extern "C" void kernel_launch(void* const* d_in, const int* in_sizes, int n_in,
                              void* d_out, int out_size, void* d_ws, size_t ws_size,
                              hipStream_t stream)
{
  const float* x         = (const float*)d_in[0];
  const float* edge_attr = (const float*)d_in[1];
  const int*   ei        = (const int*)d_in[2];   // [2][E]: row0=src, row1=dst
  const int*   batch     = (const int*)d_in[3];
  const float* Wa = (const float*)d_in[4];
  const float* ba = (const float*)d_in[5];
  const float* Wb = (const float*)d_in[6];
  const float* bb = (const float*)d_in[7];
  const float* W1 = (const float*)d_in[8];
  const float* b1 = (const float*)d_in[9];
  const float* W2 = (const float*)d_in[10];
  const float* b2 = (const float*)d_in[11];
  const float* W3 = (const float*)d_in[12];

  char* ws = (char*)d_ws;
  size_t p = 0;
  auto alloc = [&](size_t bytes) -> char* {
    char* q = ws + p;
    p += (bytes + 255) & ~(size_t)255;
    return q;
  };
  float* bufA = (float*)alloc((size_t)N_NODES * EMB * sizeof(float));          // 25.6 MB
  float* bufB = (float*)alloc((size_t)N_NODES * EMB * sizeof(float));          // 25.6 MB
  unsigned short* eemb = (unsigned short*)alloc((size_t)N_EDGES * EMB * 2);    // 128 MB
  unsigned short* w1bf = (unsigned short*)alloc(16384 * sizeof(short));
  unsigned short* w2bf = (unsigned short*)alloc(8192 * sizeof(short));
  int* deg  = (int*)alloc(N_NODES * sizeof(int));
  int* off  = (int*)alloc((N_NODES + 1) * sizeof(int));
  int* fill = (int*)alloc(N_NODES * sizeof(int));
  int* blocksum = (int*)alloc(NB_SCAN * sizeof(int));
  int* blockoff = (int*)alloc(NB_SCAN * sizeof(int));
  int* csrc = (int*)alloc((size_t)N_EDGES * sizeof(int));                      // 2 MB
  int* pos  = (int*)alloc((size_t)N_EDGES * sizeof(int));                      // 2 MB
  if (p > ws_size){
    fprintf(stderr, "kernel_launch: ws too small (%zu < %zu)\n", ws_size, p);
    return;
  }

  // CSR build
  hipMemsetAsync(deg, 0, N_NODES * sizeof(int), stream);
  count_deg<<<(N_EDGES + 255) / 256, 256, 0, stream>>>(ei, deg);
  scan_s1<<<NB_SCAN, 256, 0, stream>>>(deg, blocksum);
  scan_s2<<<1, 256, 0, stream>>>(blocksum, blockoff, off);
  scan_s3<<<NB_SCAN, 256, 0, stream>>>(deg, blockoff, off, fill);
  scatter_edges<<<(N_EDGES + 255) / 256, 256, 0, stream>>>(ei, fill, csrc, pos);

  // Embeddings: node (f32 VALU), edge (bf16 MFMA, CSR-ordered output)
  prep_mlp<<<96, 256, 0, stream>>>(W1, W2, w1bf, w2bf);
  gemm_bias<EMB, EMB, false><<<(N_NODES + 31) / 32, 256, 0, stream>>>(x, Wa, ba, bufA, N_NODES);
  edge_gemm_mfma<<<1024, 256, 0, stream>>>(edge_attr, Wb, bb, pos, eemb);

  // Two message-passing layers, gather-based, residual fused
  agg_kernel<<<(N_NODES + 7) / 8, 256, 0, stream>>>(bufA, eemb, off, csrc, bufB);
  agg_kernel<<<(N_NODES + 7) / 8, 256, 0, stream>>>(bufB, eemb, off, csrc, bufA);

  // Fused MFMA MLP + pool
  hipMemsetAsync(d_out, 0, NGRAPH * sizeof(float), stream);
  mlp_mfma_pool<<<(NSTRIP + 3) / 4, 256, 0, stream>>>(bufA, w1bf, w2bf, b1, b2, W3, batch, (float*)d_out);
}

// Round 5
// 539.075 us; speedup vs baseline: 4.5780x; 1.1708x over previous
//
#include <hip/hip_runtime.h>
#include <cstdio>
#include <cstdint>

#define N_NODES 50000
#define N_EDGES 500000
#define EMB 128
#define BOND 64
#define NGRAPH 256
#define NB_SCAN ((N_NODES + 255) / 256)   // 196 scan blocks
#define NSTRIP (N_NODES / 16)             // 3125 exact 16-node strips

typedef short bf16x8 __attribute__((ext_vector_type(8)));   // 8 bf16 (4 VGPRs)
typedef float f32x4  __attribute__((ext_vector_type(4)));

__device__ __forceinline__ unsigned short f2bf(float v){
  unsigned u = __float_as_uint(v);
  unsigned r = (u + 0x7fffu + ((u >> 16) & 1u)) >> 16;  // RNE
  return (unsigned short)r;
}
__device__ __forceinline__ float bf2f(unsigned short u){
  return __uint_as_float(((unsigned)u) << 16);
}

// ---------------- f32 GEMM (node embedding, precision headroom) ----------------
template<int K, int CO, bool BF16OUT>
__global__ __launch_bounds__(256) void gemm_bias(const float* __restrict__ in,
    const float* __restrict__ W, const float* __restrict__ bias,
    void* __restrict__ outp, long M)
{
  constexpr int KC = (K > 64) ? 64 : K;
  constexpr int NKC = K / KC;
  constexpr int LANES = CO / 4;
  constexpr int GROUPS = 256 / LANES;
  constexpr int RPB = GROUPS * 4;
  constexpr int ISTR = K + 1;
  __shared__ float wT[KC * CO];
  __shared__ float inT[RPB * ISTR];
  const int t = threadIdx.x;
  const int lc = t % LANES, g = t / LANES;
  const int c0 = lc * 4;
  const float4 bv = *(const float4*)(bias + c0);

  for (long r0 = (long)blockIdx.x * RPB; r0 < M; r0 += (long)gridDim.x * RPB){
    __syncthreads();
    for (int i = t; i < RPB * K; i += 256){
      int rr = i / K, k = i % K;
      long r = r0 + rr;
      inT[rr * ISTR + k] = (r < M) ? in[r * (long)K + k] : 0.f;
    }
    float acc[4][4];
    #pragma unroll
    for (int rr = 0; rr < 4; rr++){
      acc[rr][0] = bv.x; acc[rr][1] = bv.y; acc[rr][2] = bv.z; acc[rr][3] = bv.w;
    }
    for (int kc = 0; kc < NKC; kc++){
      __syncthreads();
      for (int i = t; i < KC * CO; i += 256){
        int c = i % CO, k = i / CO;
        wT[k * CO + c] = W[c * K + kc * KC + k];
      }
      __syncthreads();
      #pragma unroll 8
      for (int k = 0; k < KC; k++){
        float4 w = *(const float4*)&wT[k * CO + c0];
        #pragma unroll
        for (int rr = 0; rr < 4; rr++){
          float a = inT[(g * 4 + rr) * ISTR + kc * KC + k];
          acc[rr][0] = fmaf(a, w.x, acc[rr][0]);
          acc[rr][1] = fmaf(a, w.y, acc[rr][1]);
          acc[rr][2] = fmaf(a, w.z, acc[rr][2]);
          acc[rr][3] = fmaf(a, w.w, acc[rr][3]);
        }
      }
    }
    #pragma unroll
    for (int rr = 0; rr < 4; rr++){
      long r = r0 + g * 4 + rr;
      if (r < M){
        if (BF16OUT){
          ushort4 o;
          o.x = f2bf(acc[rr][0]); o.y = f2bf(acc[rr][1]);
          o.z = f2bf(acc[rr][2]); o.w = f2bf(acc[rr][3]);
          *(ushort4*)((unsigned short*)outp + r * CO + c0) = o;
        } else {
          float4 o = make_float4(acc[rr][0], acc[rr][1], acc[rr][2], acc[rr][3]);
          *(float4*)((float*)outp + r * CO + c0) = o;
        }
      }
    }
  }
}

// ---------------- bf16 MFMA edge GEMM, writes eemb in CSR order ----------------
__global__ __launch_bounds__(256) void edge_gemm_mfma(
    const float* __restrict__ attr, const float* __restrict__ Wb,
    const float* __restrict__ bb, const int* __restrict__ pos,
    unsigned short* __restrict__ eemb)
{
  const int t = threadIdx.x;
  const int wv = t >> 6;
  const int l  = t & 63;
  const int lm = l & 15;
  const int q  = l >> 4;
  union U8 { bf16x8 v; unsigned short s[8]; };

  bf16x8 bfrag[8][2];
  float bias[8];
  #pragma unroll
  for (int tn = 0; tn < 8; tn++){
    bias[tn] = bb[tn * 16 + lm];
    #pragma unroll
    for (int h = 0; h < 2; h++){
      const float* wp = Wb + (tn * 16 + lm) * BOND + h * 32 + q * 8;
      float4 w0 = *(const float4*)wp;
      float4 w1 = *(const float4*)(wp + 4);
      U8 u;
      u.s[0] = f2bf(w0.x); u.s[1] = f2bf(w0.y); u.s[2] = f2bf(w0.z); u.s[3] = f2bf(w0.w);
      u.s[4] = f2bf(w1.x); u.s[5] = f2bf(w1.y); u.s[6] = f2bf(w1.z); u.s[7] = f2bf(w1.w);
      bfrag[tn][h] = u.v;
    }
  }

  const long stride = (long)gridDim.x * 4 * 16;
  for (long r0 = ((long)blockIdx.x * 4 + wv) * 16; r0 < N_EDGES; r0 += stride){
    long rm = r0 + lm;
    bool valid = rm < N_EDGES;
    bf16x8 afrag[2];
    #pragma unroll
    for (int h = 0; h < 2; h++){
      float4 a0 = make_float4(0.f,0.f,0.f,0.f), a1 = a0;
      if (valid){
        const float* ap = attr + rm * (long)BOND + h * 32 + q * 8;
        a0 = *(const float4*)ap;
        a1 = *(const float4*)(ap + 4);
      }
      U8 u;
      u.s[0] = f2bf(a0.x); u.s[1] = f2bf(a0.y); u.s[2] = f2bf(a0.z); u.s[3] = f2bf(a0.w);
      u.s[4] = f2bf(a1.x); u.s[5] = f2bf(a1.y); u.s[6] = f2bf(a1.z); u.s[7] = f2bf(a1.w);
      afrag[h] = u.v;
    }
    long pr[4];
    #pragma unroll
    for (int i = 0; i < 4; i++){
      long r = r0 + q * 4 + i;
      pr[i] = (r < N_EDGES) ? (long)pos[r] : -1;
    }
    #pragma unroll
    for (int tn = 0; tn < 8; tn++){
      f32x4 acc = {0.f, 0.f, 0.f, 0.f};
      acc = __builtin_amdgcn_mfma_f32_16x16x32_bf16(afrag[0], bfrag[tn][0], acc, 0, 0, 0);
      acc = __builtin_amdgcn_mfma_f32_16x16x32_bf16(afrag[1], bfrag[tn][1], acc, 0, 0, 0);
      #pragma unroll
      for (int i = 0; i < 4; i++){
        if (pr[i] >= 0)
          eemb[pr[i] * EMB + tn * 16 + lm] = f2bf(acc[i] + bias[tn]);
      }
    }
  }
}

// ---------------- CSR build (by dst) ----------------

__global__ __launch_bounds__(256) void count_deg(const int* __restrict__ ei,
                                                 int* __restrict__ deg)
{
  int e = blockIdx.x * 256 + threadIdx.x;
  if (e < N_EDGES) atomicAdd(&deg[ei[N_EDGES + e]], 1);
}

__global__ __launch_bounds__(256) void scan_s1(const int* __restrict__ deg,
                                               int* __restrict__ blocksum)
{
  int i = blockIdx.x * 256 + threadIdx.x;
  int lane = threadIdx.x & 63, w = threadIdx.x >> 6;
  int v = (i < N_NODES) ? deg[i] : 0;
  #pragma unroll
  for (int o = 32; o > 0; o >>= 1) v += __shfl_down(v, o, 64);
  __shared__ int ws4[4];
  if (lane == 0) ws4[w] = v;
  __syncthreads();
  if (threadIdx.x == 0) blocksum[blockIdx.x] = ws4[0] + ws4[1] + ws4[2] + ws4[3];
}

__global__ __launch_bounds__(256) void scan_s2(const int* __restrict__ blocksum,
                                               int* __restrict__ blockoff,
                                               int* __restrict__ off)
{
  int t = threadIdx.x;
  int lane = t & 63, w = t >> 6;
  int v = (t < NB_SCAN) ? blocksum[t] : 0;
  int x = v;
  #pragma unroll
  for (int d = 1; d < 64; d <<= 1){
    int y = __shfl_up(x, d, 64);
    if (lane >= d) x += y;
  }
  __shared__ int wsum[4];
  if (lane == 63) wsum[w] = x;
  __syncthreads();
  int wo = 0;
  for (int j = 0; j < w; j++) wo += wsum[j];
  if (t < NB_SCAN) blockoff[t] = wo + x - v;
  if (t == 0) off[N_NODES] = wsum[0] + wsum[1] + wsum[2] + wsum[3];
}

__global__ __launch_bounds__(256) void scan_s3(const int* __restrict__ deg,
    const int* __restrict__ blockoff, int* __restrict__ off, int* __restrict__ fill)
{
  int i = blockIdx.x * 256 + threadIdx.x;
  int lane = threadIdx.x & 63, w = threadIdx.x >> 6;
  int v = (i < N_NODES) ? deg[i] : 0;
  int x = v;
  #pragma unroll
  for (int d = 1; d < 64; d <<= 1){
    int y = __shfl_up(x, d, 64);
    if (lane >= d) x += y;
  }
  __shared__ int wsum[4];
  if (lane == 63) wsum[w] = x;
  __syncthreads();
  int wo = 0;
  for (int j = 0; j < w; j++) wo += wsum[j];
  if (i < N_NODES){
    int excl = blockoff[blockIdx.x] + wo + x - v;
    off[i] = excl;
    fill[i] = excl;
  }
}

__global__ __launch_bounds__(256) void scatter_edges(const int* __restrict__ ei,
    int* __restrict__ fill, int* __restrict__ csrc, int* __restrict__ pos)
{
  int e = blockIdx.x * 256 + threadIdx.x;
  if (e < N_EDGES){
    int dst = ei[N_EDGES + e];
    int p = atomicAdd(&fill[dst], 1);
    csrc[p] = ei[e];
    pos[e] = p;
  }
}

// ---------------- gather aggregation (residual fused, eemb CSR-ordered) ----------------
// Unrolled 4x with two accumulators: 4 independent row-gathers in flight per wave
// (was 1 — the serial csrc->gather->fma chain was the latency bottleneck).
__global__ __launch_bounds__(256) void agg_kernel(const float* __restrict__ node_old,
    const unsigned short* __restrict__ eemb, const int* __restrict__ off,
    const int* __restrict__ csrc, float* __restrict__ node_new)
{
  int n = blockIdx.x * 8 + (threadIdx.x >> 5);
  if (n >= N_NODES) return;
  int c0 = (threadIdx.x & 31) * 4;
  int s = off[n], e = off[n + 1];
  float4 accA = *(const float4*)(node_old + (long)n * EMB + c0);  // residual
  float4 accB = make_float4(0.f, 0.f, 0.f, 0.f);
  int i = s;
  for (; i + 4 <= e; i += 4){
    int s0 = csrc[i], s1 = csrc[i + 1], s2 = csrc[i + 2], s3 = csrc[i + 3];
    float4 a0 = *(const float4*)(node_old + (long)s0 * EMB + c0);
    float4 a1 = *(const float4*)(node_old + (long)s1 * EMB + c0);
    float4 a2 = *(const float4*)(node_old + (long)s2 * EMB + c0);
    float4 a3 = *(const float4*)(node_old + (long)s3 * EMB + c0);
    ushort4 e0 = *(const ushort4*)(eemb + (long)i * EMB + c0);
    ushort4 e1 = *(const ushort4*)(eemb + (long)(i + 1) * EMB + c0);
    ushort4 e2 = *(const ushort4*)(eemb + (long)(i + 2) * EMB + c0);
    ushort4 e3 = *(const ushort4*)(eemb + (long)(i + 3) * EMB + c0);
    accA.x = fmaf(a0.x, bf2f(e0.x), accA.x);
    accA.y = fmaf(a0.y, bf2f(e0.y), accA.y);
    accA.z = fmaf(a0.z, bf2f(e0.z), accA.z);
    accA.w = fmaf(a0.w, bf2f(e0.w), accA.w);
    accB.x = fmaf(a1.x, bf2f(e1.x), accB.x);
    accB.y = fmaf(a1.y, bf2f(e1.y), accB.y);
    accB.z = fmaf(a1.z, bf2f(e1.z), accB.z);
    accB.w = fmaf(a1.w, bf2f(e1.w), accB.w);
    accA.x = fmaf(a2.x, bf2f(e2.x), accA.x);
    accA.y = fmaf(a2.y, bf2f(e2.y), accA.y);
    accA.z = fmaf(a2.z, bf2f(e2.z), accA.z);
    accA.w = fmaf(a2.w, bf2f(e2.w), accA.w);
    accB.x = fmaf(a3.x, bf2f(e3.x), accB.x);
    accB.y = fmaf(a3.y, bf2f(e3.y), accB.y);
    accB.z = fmaf(a3.z, bf2f(e3.z), accB.z);
    accB.w = fmaf(a3.w, bf2f(e3.w), accB.w);
  }
  for (; i < e; i++){
    int src = csrc[i];
    const float4 a = *(const float4*)(node_old + (long)src * EMB + c0);
    ushort4 eb = *(const ushort4*)(eemb + (long)i * EMB + c0);
    accA.x = fmaf(a.x, bf2f(eb.x), accA.x);
    accA.y = fmaf(a.y, bf2f(eb.y), accA.y);
    accA.z = fmaf(a.z, bf2f(eb.z), accA.z);
    accA.w = fmaf(a.w, bf2f(eb.w), accA.w);
  }
  accA.x += accB.x; accA.y += accB.y; accA.z += accB.z; accA.w += accB.w;
  *(float4*)(node_new + (long)n * EMB + c0) = accA;
}

// ---------------- MLP weight prep: fragment-linear bf16 ----------------
__global__ void prep_mlp(const float* __restrict__ W1, const float* __restrict__ W2,
                         unsigned short* __restrict__ w1bf, unsigned short* __restrict__ w2bf)
{
  int i = blockIdx.x * 256 + threadIdx.x;
  if (i < 16384){
    int j = i & 7, lb = (i >> 3) & 63, kc = (i >> 9) & 3, tn = i >> 11;
    int lm = lb & 15, q = lb >> 4;
    w1bf[i] = f2bf(W1[(tn * 16 + lm) * EMB + kc * 32 + q * 8 + j]);
  } else if (i < 16384 + 8192){
    int i2 = i - 16384;
    int j = i2 & 7, lb = (i2 >> 3) & 63, kc = (i2 >> 9) & 3, tc = i2 >> 11;
    int lm = lb & 15, q = lb >> 4;
    w2bf[i2] = f2bf(W2[(tc * 16 + lm) * EMB + kc * 32 + q * 8 + j]);
  }
}

// ---------------- fused MFMA MLP + block-pooled reduction ----------------
// R4 lesson: 50k direct global atomics into dg[256] (16 cachelines) serialize at the
// L2 atomic unit (~100 us). Pool per-block in LDS, flush nonzero entries only
// (~2 global atomics per block).
__global__ __launch_bounds__(256) void mlp_mfma_pool(const float* __restrict__ ne,
    const unsigned short* __restrict__ w1bf, const unsigned short* __restrict__ w2bf,
    const float* __restrict__ b1, const float* __restrict__ b2,
    const float* __restrict__ W3, const int* __restrict__ batch,
    float* __restrict__ dg)
{
  __shared__ float h1s[4][16 * 132];   // per-wave scratch
  __shared__ float pool[NGRAPH];       // per-block graph accumulator
  const int t = threadIdx.x;
  const int wv = t >> 6, l = t & 63;
  const int lm = l & 15, q = l >> 4;
  union U8 { bf16x8 v; unsigned short s[8]; };

  for (int i = t; i < NGRAPH; i += 256) pool[i] = 0.f;
  __syncthreads();

  const int strip = blockIdx.x * 4 + wv;
  if (strip < NSTRIP){
    const long n0 = (long)strip * 16;

    float b1v[8], b2v[4], w3v[4];
    #pragma unroll
    for (int tn = 0; tn < 8; tn++) b1v[tn] = b1[tn * 16 + lm];
    #pragma unroll
    for (int tc = 0; tc < 4; tc++){ b2v[tc] = b2[tc * 16 + lm]; w3v[tc] = W3[tc * 16 + lm]; }

    // A-fragments of relu(ne) : A[m=lm][k=kc*32+q*8+j]
    bf16x8 a1[4];
    #pragma unroll
    for (int kc = 0; kc < 4; kc++){
      const float* ap = ne + (n0 + lm) * EMB + kc * 32 + q * 8;
      float4 x0 = *(const float4*)ap;
      float4 x1 = *(const float4*)(ap + 4);
      U8 u;
      u.s[0] = f2bf(fmaxf(x0.x, 0.f)); u.s[1] = f2bf(fmaxf(x0.y, 0.f));
      u.s[2] = f2bf(fmaxf(x0.z, 0.f)); u.s[3] = f2bf(fmaxf(x0.w, 0.f));
      u.s[4] = f2bf(fmaxf(x1.x, 0.f)); u.s[5] = f2bf(fmaxf(x1.y, 0.f));
      u.s[6] = f2bf(fmaxf(x1.z, 0.f)); u.s[7] = f2bf(fmaxf(x1.w, 0.f));
      a1[kc] = u.v;
    }

    // Layer 1
    f32x4 acc1[8];
    #pragma unroll
    for (int tn = 0; tn < 8; tn++) acc1[tn] = (f32x4){b1v[tn], b1v[tn], b1v[tn], b1v[tn]};
    #pragma unroll
    for (int kc = 0; kc < 4; kc++){
      #pragma unroll
      for (int tn = 0; tn < 8; tn++){
        bf16x8 bf = *(const bf16x8*)(w1bf + (size_t)((tn * 4 + kc) * 64 + l) * 8);
        acc1[tn] = __builtin_amdgcn_mfma_f32_16x16x32_bf16(a1[kc], bf, acc1[tn], 0, 0, 0);
      }
    }

    // relu -> LDS (C layout -> row-major) -> A-fragments for layer 2
    float* h1 = h1s[wv];
    #pragma unroll
    for (int tn = 0; tn < 8; tn++)
      #pragma unroll
      for (int i = 0; i < 4; i++)
        h1[(q * 4 + i) * 132 + tn * 16 + lm] = fmaxf(acc1[tn][i], 0.f);
    bf16x8 a2[4];
    #pragma unroll
    for (int kc = 0; kc < 4; kc++){
      const float* hp = h1 + lm * 132 + kc * 32 + q * 8;
      float4 x0 = *(const float4*)hp;
      float4 x1 = *(const float4*)(hp + 4);
      U8 u;
      u.s[0] = f2bf(x0.x); u.s[1] = f2bf(x0.y); u.s[2] = f2bf(x0.z); u.s[3] = f2bf(x0.w);
      u.s[4] = f2bf(x1.x); u.s[5] = f2bf(x1.y); u.s[6] = f2bf(x1.z); u.s[7] = f2bf(x1.w);
      a2[kc] = u.v;
    }

    // Layer 2
    f32x4 acc2[4];
    #pragma unroll
    for (int tc = 0; tc < 4; tc++) acc2[tc] = (f32x4){b2v[tc], b2v[tc], b2v[tc], b2v[tc]};
    #pragma unroll
    for (int kc = 0; kc < 4; kc++){
      #pragma unroll
      for (int tc = 0; tc < 4; tc++){
        bf16x8 bf = *(const bf16x8*)(w2bf + (size_t)((tc * 4 + kc) * 64 + l) * 8);
        acc2[tc] = __builtin_amdgcn_mfma_f32_16x16x32_bf16(a2[kc], bf, acc2[tc], 0, 0, 0);
      }
    }

    // Layer 3 + 16-lane reduce, then LDS pool (low-contention ds_add)
    float e4[4];
    #pragma unroll
    for (int i = 0; i < 4; i++){
      float s = 0.f;
      #pragma unroll
      for (int tc = 0; tc < 4; tc++) s = fmaf(fmaxf(acc2[tc][i], 0.f), w3v[tc], s);
      e4[i] = s;
    }
    #pragma unroll
    for (int m = 1; m < 16; m <<= 1)
      #pragma unroll
      for (int i = 0; i < 4; i++) e4[i] += __shfl_xor(e4[i], m, 64);
    if (lm == 0){
      #pragma unroll
      for (int i = 0; i < 4; i++){
        int node = (int)n0 + q * 4 + i;
        atomicAdd(&pool[batch[node]], e4[i]);
      }
    }
  }
  __syncthreads();
  for (int i = t; i < NGRAPH; i += 256){
    float v = pool[i];
    if (v != 0.f) atomicAdd(&dg[i], v);
  }
}

extern "C" void kernel_launch(void* const* d_in, const int* in_sizes, int n_in,
                              void* d_out, int out_size, void* d_ws, size_t ws_size,
                              hipStream_t stream)
{
  const float* x         = (const float*)d_in[0];
  const float* edge_attr = (const float*)d_in[1];
  const int*   ei        = (const int*)d_in[2];   // [2][E]: row0=src, row1=dst
  const int*   batch     = (const int*)d_in[3];
  const float* Wa = (const float*)d_in[4];
  const float* ba = (const float*)d_in[5];
  const float* Wb = (const float*)d_in[6];
  const float* bb = (const float*)d_in[7];
  const float* W1 = (const float*)d_in[8];
  const float* b1 = (const float*)d_in[9];
  const float* W2 = (const float*)d_in[10];
  const float* b2 = (const float*)d_in[11];
  const float* W3 = (const float*)d_in[12];

  char* ws = (char*)d_ws;
  size_t p = 0;
  auto alloc = [&](size_t bytes) -> char* {
    char* q = ws + p;
    p += (bytes + 255) & ~(size_t)255;
    return q;
  };
  float* bufA = (float*)alloc((size_t)N_NODES * EMB * sizeof(float));          // 25.6 MB
  float* bufB = (float*)alloc((size_t)N_NODES * EMB * sizeof(float));          // 25.6 MB
  unsigned short* eemb = (unsigned short*)alloc((size_t)N_EDGES * EMB * 2);    // 128 MB
  unsigned short* w1bf = (unsigned short*)alloc(16384 * sizeof(short));
  unsigned short* w2bf = (unsigned short*)alloc(8192 * sizeof(short));
  int* deg  = (int*)alloc(N_NODES * sizeof(int));
  int* off  = (int*)alloc((N_NODES + 1) * sizeof(int));
  int* fill = (int*)alloc(N_NODES * sizeof(int));
  int* blocksum = (int*)alloc(NB_SCAN * sizeof(int));
  int* blockoff = (int*)alloc(NB_SCAN * sizeof(int));
  int* csrc = (int*)alloc((size_t)N_EDGES * sizeof(int));                      // 2 MB
  int* pos  = (int*)alloc((size_t)N_EDGES * sizeof(int));                      // 2 MB
  if (p > ws_size){
    fprintf(stderr, "kernel_launch: ws too small (%zu < %zu)\n", ws_size, p);
    return;
  }

  // CSR build
  hipMemsetAsync(deg, 0, N_NODES * sizeof(int), stream);
  count_deg<<<(N_EDGES + 255) / 256, 256, 0, stream>>>(ei, deg);
  scan_s1<<<NB_SCAN, 256, 0, stream>>>(deg, blocksum);
  scan_s2<<<1, 256, 0, stream>>>(blocksum, blockoff, off);
  scan_s3<<<NB_SCAN, 256, 0, stream>>>(deg, blockoff, off, fill);
  scatter_edges<<<(N_EDGES + 255) / 256, 256, 0, stream>>>(ei, fill, csrc, pos);

  // Embeddings: node (f32 VALU), edge (bf16 MFMA, CSR-ordered output)
  prep_mlp<<<96, 256, 0, stream>>>(W1, W2, w1bf, w2bf);
  gemm_bias<EMB, EMB, false><<<(N_NODES + 31) / 32, 256, 0, stream>>>(x, Wa, ba, bufA, N_NODES);
  edge_gemm_mfma<<<1024, 256, 0, stream>>>(edge_attr, Wb, bb, pos, eemb);

  // Two message-passing layers, gather-based, residual fused
  agg_kernel<<<(N_NODES + 7) / 8, 256, 0, stream>>>(bufA, eemb, off, csrc, bufB);
  agg_kernel<<<(N_NODES + 7) / 8, 256, 0, stream>>>(bufB, eemb, off, csrc, bufA);

  // Fused MFMA MLP + pool
  hipMemsetAsync(d_out, 0, NGRAPH * sizeof(float), stream);
  mlp_mfma_pool<<<(NSTRIP + 3) / 4, 256, 0, stream>>>(bufA, w1bf, w2bf, b1, b2, W3, batch, (float*)d_out);
}